// Round 1
// baseline (39520.236 us; speedup 1.0000x reference)
//
#include <hip/hip_runtime.h>
#include <cstddef>
#include <cstdint>

// Problem constants
#define Tn 52
#define Fn 64
#define Hn 32
#define Bn 8192
#define XHAT_ELEMS (Bn * Tn * Fn)   // 27,262,976 == [T,B,64] scratch size too

__device__ __forceinline__ float sigm(float x)  { return 1.f / (1.f + __expf(-x)); }
__device__ __forceinline__ float tanh_f(float x){ return 1.f - 2.f / (__expf(2.f * x) + 1.f); }

// One LSTM unit's 4 gate dot-products (K = 64 input + 32 hidden) + state update.
// Weights read from global (L2-resident). x4/h4 live in registers (fully unrolled,
// constant indices -> SROA to VGPRs).
__device__ __forceinline__ void cell_unit(const float* __restrict__ Wih,
                                          const float* __restrict__ Whh,
                                          size_t cellRow,   // cell_index * 128
                                          int j,            // hidden unit [0,32)
                                          const float4* __restrict__ x4,  // [16]
                                          const float4* __restrict__ h4,  // [8]
                                          float bi, float bf, float bg, float bo,
                                          float& cstate, float& hout)
{
    const float4* wi = (const float4*)(Wih + (cellRow + j      ) * 64);
    const float4* wf = (const float4*)(Wih + (cellRow + 32 + j ) * 64);
    const float4* wg = (const float4*)(Wih + (cellRow + 64 + j ) * 64);
    const float4* wo = (const float4*)(Wih + (cellRow + 96 + j ) * 64);
    float ai = bi, af = bf, ag = bg, ao = bo;
#pragma unroll
    for (int k = 0; k < 16; ++k) {
        float4 xv = x4[k];
        float4 a = wi[k]; ai += a.x*xv.x + a.y*xv.y + a.z*xv.z + a.w*xv.w;
        float4 b = wf[k]; af += b.x*xv.x + b.y*xv.y + b.z*xv.z + b.w*xv.w;
        float4 g = wg[k]; ag += g.x*xv.x + g.y*xv.y + g.z*xv.z + g.w*xv.w;
        float4 o = wo[k]; ao += o.x*xv.x + o.y*xv.y + o.z*xv.z + o.w*xv.w;
    }
    const float4* vi = (const float4*)(Whh + (cellRow + j      ) * 32);
    const float4* vf = (const float4*)(Whh + (cellRow + 32 + j ) * 32);
    const float4* vg = (const float4*)(Whh + (cellRow + 64 + j ) * 32);
    const float4* vo = (const float4*)(Whh + (cellRow + 96 + j ) * 32);
#pragma unroll
    for (int k = 0; k < 8; ++k) {
        float4 hv = h4[k];
        float4 a = vi[k]; ai += a.x*hv.x + a.y*hv.y + a.z*hv.z + a.w*hv.w;
        float4 b = vf[k]; af += b.x*hv.x + b.y*hv.y + b.z*hv.z + b.w*hv.w;
        float4 g = vg[k]; ag += g.x*hv.x + g.y*hv.y + g.z*hv.z + g.w*hv.w;
        float4 o = vo[k]; ao += o.x*hv.x + o.y*hv.y + o.z*hv.z + o.w*hv.w;
    }
    float si = sigm(ai), sf = sigm(af), tg = tanh_f(ag), so = sigm(ao);
    cstate = sf * cstate + si * tg;
    hout   = so * tanh_f(cstate);
}

// One bidirectional encoder layer. Block = 512 threads = 8 waves, owns 32 rows.
// Wave w: direction d = w>>2, units j0 = 8*(w&3)+4*jh (jh = lane>>5), 4 units/lane.
// h exchanged via LDS (pad 33 -> conflict-free); c kept in registers.
__global__ __launch_bounds__(512, 2)
void enc_layer_kernel(const float* __restrict__ X, long sb, long st,
                      const float* __restrict__ h0, const float* __restrict__ c0,
                      const float* __restrict__ Wih, const float* __restrict__ Whh,
                      const float* __restrict__ bias,
                      int layer, float* __restrict__ xs_out, float* __restrict__ z)
{
    __shared__ float hbuf[2][32][33];
    const int tid  = threadIdx.x;
    const int w    = tid >> 6;
    const int lane = tid & 63;
    const int r    = lane & 31;
    const int jh   = lane >> 5;
    const int d    = w >> 2;
    const int j0   = 8 * (w & 3) + 4 * jh;
    const int row0 = blockIdx.x * 32;
    const int row  = row0 + r;
    const int ci   = 2 * layer + d;

    for (int idx = tid; idx < 2 * 32 * 32; idx += 512) {
        int dd = idx >> 10, rr = (idx >> 5) & 31, jj = idx & 31;
        hbuf[dd][rr][jj] = h0[((size_t)(2 * layer + dd) * Bn + (row0 + rr)) * Hn + jj];
    }
    float c[4], h2[4];
#pragma unroll
    for (int u = 0; u < 4; ++u) c[u] = c0[((size_t)ci * Bn + row) * Hn + (j0 + u)];
    float bI[4], bF[4], bG[4], bO[4];
#pragma unroll
    for (int u = 0; u < 4; ++u) {
        bI[u] = bias[d * 128 +      (j0 + u)];
        bF[u] = bias[d * 128 + 32 + (j0 + u)];
        bG[u] = bias[d * 128 + 64 + (j0 + u)];
        bO[u] = bias[d * 128 + 96 + (j0 + u)];
    }
    __syncthreads();

    for (int t = 0; t < Tn; ++t) {
        const int tt = d ? (Tn - 1 - t) : t;
        float4 x4[16];
        const float4* xp = (const float4*)(X + (size_t)row * sb + (size_t)tt * st);
#pragma unroll
        for (int k = 0; k < 16; ++k) x4[k] = xp[k];
        float4 h4[8];
#pragma unroll
        for (int k = 0; k < 8; ++k)
            h4[k] = make_float4(hbuf[d][r][4*k], hbuf[d][r][4*k+1],
                                hbuf[d][r][4*k+2], hbuf[d][r][4*k+3]);
#pragma unroll
        for (int u = 0; u < 4; ++u)
            cell_unit(Wih, Whh, (size_t)d * 128, j0 + u, x4, h4,
                      bI[u], bF[u], bG[u], bO[u], c[u], h2[u]);
        __syncthreads();   // all lanes done reading hbuf
#pragma unroll
        for (int u = 0; u < 4; ++u) hbuf[d][r][j0 + u] = h2[u];
        __syncthreads();   // writes visible
        if (xs_out) {
            // cooperative coalesced store: 2048 floats, one float4 per thread
            int idx = tid * 4;
            int rr = idx >> 6, cc = idx & 63;
            int dd = cc >> 5, jj = cc & 31;
            int ttd = dd ? (Tn - 1 - t) : t;
            float4 v = make_float4(hbuf[dd][rr][jj], hbuf[dd][rr][jj+1],
                                   hbuf[dd][rr][jj+2], hbuf[dd][rr][jj+3]);
            *(float4*)(xs_out + ((size_t)ttd * Bn + (row0 + rr)) * Fn + cc) = v;
        }
    }
    // final states -> z : h at ci*32, c at 128 + ci*32
#pragma unroll
    for (int u = 0; u < 4; ++u) {
        z[(size_t)row * 256 +       ci * 32 + (j0 + u)] = h2[u];
        z[(size_t)row * 256 + 128 + ci * 32 + (j0 + u)] = c[u];
    }
}

// Autoregressive decoder: 52 steps, per step phase A = layer0 cells (l0f,l0b),
// phase B = layer1 cells. All 512 lanes active in both phases (4 units/lane/phase).
__global__ __launch_bounds__(512, 2)
void dec_kernel(const float* __restrict__ Wih, const float* __restrict__ Whh,
                const float* __restrict__ bias, const float* __restrict__ z,
                float* __restrict__ xhat)
{
    __shared__ float hbuf[4][32][33];
    __shared__ float ybuf[32][65];   // layer-1 output == next step input
    __shared__ float mbuf[32][65];   // layer-0 output (mid)
    const int tid  = threadIdx.x;
    const int w    = tid >> 6;
    const int lane = tid & 63;
    const int r    = lane & 31;
    const int jh   = lane >> 5;
    const int dA   = w >> 2;
    const int j0   = 8 * (w & 3) + 4 * jh;
    const int cA   = dA;        // layer0 cell index (0=l0f,1=l0b)
    const int cB   = 2 + dA;    // layer1 cell index (2=l1f,3=l1b)
    const int row0 = blockIdx.x * 32;
    const int row  = row0 + r;

    for (int idx = tid; idx < 4 * 32 * 32; idx += 512) {
        int cell = idx >> 10, rr = (idx >> 5) & 31, jj = idx & 31;
        hbuf[cell][rr][jj] = z[(size_t)(row0 + rr) * 256 + cell * 32 + jj];
    }
    for (int idx = tid; idx < 32 * 65; idx += 512) (&ybuf[0][0])[idx] = 0.f;  // out0 = zeros
    float cAr[4], cBr[4], hA[4], hB[4];
#pragma unroll
    for (int u = 0; u < 4; ++u) {
        cAr[u] = z[(size_t)row * 256 + 128 + cA * 32 + (j0 + u)];
        cBr[u] = z[(size_t)row * 256 + 128 + cB * 32 + (j0 + u)];
    }
    float bAi[4], bAf[4], bAg[4], bAo[4], bBi[4], bBf[4], bBg[4], bBo[4];
#pragma unroll
    for (int u = 0; u < 4; ++u) {
        bAi[u] = bias[cA * 128 +      (j0 + u)];
        bAf[u] = bias[cA * 128 + 32 + (j0 + u)];
        bAg[u] = bias[cA * 128 + 64 + (j0 + u)];
        bAo[u] = bias[cA * 128 + 96 + (j0 + u)];
        bBi[u] = bias[cB * 128 +      (j0 + u)];
        bBf[u] = bias[cB * 128 + 32 + (j0 + u)];
        bBg[u] = bias[cB * 128 + 64 + (j0 + u)];
        bBo[u] = bias[cB * 128 + 96 + (j0 + u)];
    }
    __syncthreads();

    for (int t = 0; t < Tn; ++t) {
        // ---- phase A: layer 0 ----
        float4 x4[16], h4[8];
#pragma unroll
        for (int k = 0; k < 16; ++k)
            x4[k] = make_float4(ybuf[r][4*k], ybuf[r][4*k+1], ybuf[r][4*k+2], ybuf[r][4*k+3]);
#pragma unroll
        for (int k = 0; k < 8; ++k)
            h4[k] = make_float4(hbuf[cA][r][4*k], hbuf[cA][r][4*k+1],
                                hbuf[cA][r][4*k+2], hbuf[cA][r][4*k+3]);
#pragma unroll
        for (int u = 0; u < 4; ++u)
            cell_unit(Wih, Whh, (size_t)cA * 128, j0 + u, x4, h4,
                      bAi[u], bAf[u], bAg[u], bAo[u], cAr[u], hA[u]);
        __syncthreads();
#pragma unroll
        for (int u = 0; u < 4; ++u) {
            hbuf[cA][r][j0 + u]      = hA[u];
            mbuf[r][dA * 32 + j0 + u] = hA[u];
        }
        __syncthreads();
        // ---- phase B: layer 1 ----
#pragma unroll
        for (int k = 0; k < 16; ++k)
            x4[k] = make_float4(mbuf[r][4*k], mbuf[r][4*k+1], mbuf[r][4*k+2], mbuf[r][4*k+3]);
#pragma unroll
        for (int k = 0; k < 8; ++k)
            h4[k] = make_float4(hbuf[cB][r][4*k], hbuf[cB][r][4*k+1],
                                hbuf[cB][r][4*k+2], hbuf[cB][r][4*k+3]);
#pragma unroll
        for (int u = 0; u < 4; ++u)
            cell_unit(Wih, Whh, (size_t)cB * 128, j0 + u, x4, h4,
                      bBi[u], bBf[u], bBg[u], bBo[u], cBr[u], hB[u]);
        __syncthreads();
#pragma unroll
        for (int u = 0; u < 4; ++u) {
            hbuf[cB][r][j0 + u]      = hB[u];
            ybuf[r][dA * 32 + j0 + u] = hB[u];
        }
        __syncthreads();
        // cooperative coalesced store of y -> x_hat[b][t][:]
        {
            int rr = tid >> 4;
            int cc = (tid & 15) * 4;
            float4 v = make_float4(ybuf[rr][cc], ybuf[rr][cc+1], ybuf[rr][cc+2], ybuf[rr][cc+3]);
            *(float4*)(xhat + ((size_t)(row0 + rr) * Tn + t) * Fn + cc) = v;
        }
    }
}

extern "C" void kernel_launch(void* const* d_in, const int* in_sizes, int n_in,
                              void* d_out, int out_size, void* d_ws, size_t ws_size,
                              hipStream_t stream) {
    const float* x    = (const float*)d_in[0];
    const float* h0   = (const float*)d_in[1];
    const float* c0   = (const float*)d_in[2];
    const float* eWih = (const float*)d_in[3];
    const float* eWhh = (const float*)d_in[4];
    const float* eb   = (const float*)d_in[5];
    const float* dWih = (const float*)d_in[6];
    const float* dWhh = (const float*)d_in[7];
    const float* db   = (const float*)d_in[8];

    float* out = (float*)d_out;
    float* xs1 = out;                      // [T,B,64] scratch, later overwritten by x_hat
    float* zb  = out + (size_t)XHAT_ELEMS; // [B,256] latent code

    dim3 grid(Bn / 32), block(512);
    // encoder layer 0: input x [B,T,F] -> xs1 [T,B,64] + z slots 0,1 (+c)
    hipLaunchKernelGGL(enc_layer_kernel, grid, block, 0, stream,
                       x, (long)(Tn * Fn), (long)Fn, h0, c0,
                       eWih, eWhh, eb, 0, xs1, zb);
    // encoder layer 1: input xs1 [T,B,64] -> z slots 2,3 (+c); no sequence output
    hipLaunchKernelGGL(enc_layer_kernel, grid, block, 0, stream,
                       xs1, (long)Fn, (long)(Bn * Fn), h0, c0,
                       eWih + 2 * 128 * 64, eWhh + 2 * 128 * 32, eb + 256,
                       1, (float*)nullptr, zb);
    // decoder: z -> x_hat (overwrites xs1 region)
    hipLaunchKernelGGL(dec_kernel, grid, block, 0, stream,
                       dWih, dWhh, db, zb, out);
}

// Round 2
// 485.118 us; speedup vs baseline: 81.4652x; 81.4652x over previous
//
#include <hip/hip_runtime.h>
#include <hip/hip_bf16.h>
#include <cstddef>
#include <cstdint>

#define Tn 52
#define Fn 64
#define Hn 32
#define Bn 8192
#define XHAT_ELEMS (Bn * Tn * Fn)   // fp32 elems of x_hat; also == 2 bf16 arrays [T,B,64]

typedef __attribute__((ext_vector_type(8))) short bf8v;   // 8 bf16 (4 VGPRs)
typedef __attribute__((ext_vector_type(4))) float f4v;    // 4 fp32 accum

__device__ __forceinline__ float sigm(float x)  { return 1.f / (1.f + __expf(-x)); }
__device__ __forceinline__ float tanh_f(float x){ return 1.f - 2.f / (__expf(2.f * x) + 1.f); }

__device__ __forceinline__ f4v mfma_bf16(bf8v a, bf8v b, f4v c) {
    return __builtin_amdgcn_mfma_f32_16x16x32_bf16(a, b, c, 0, 0, 0);
}

__device__ __forceinline__ void split_bf(float v, __hip_bfloat16& hi, __hip_bfloat16& lo) {
    hi = __float2bfloat16(v);
    lo = __float2bfloat16(v - __bfloat162float(hi));
}

// ---------------------------------------------------------------------------
// Prep: weights -> fragment-ordered bf16 hi/lo arrays in ws.
// Frag layout: [grp(enc,dec)][cell(4)][ntile(8)][kiter(3)][lane(64)][j(8)]
//   gate = ntile*16 + (lane&15); k = kiter*32 + (lane>>4)*8 + j
//   k<64 -> Wih[cell][gate][k], else Whh[cell][gate][k-64]
// hi at grp*98304 + idx ; lo at +49152 within the group block.
// ---------------------------------------------------------------------------
__global__ void prep_kernel(const float* __restrict__ eWih, const float* __restrict__ eWhh,
                            const float* __restrict__ dWih, const float* __restrict__ dWhh,
                            __hip_bfloat16* __restrict__ ws)
{
    int fid = blockIdx.x * 256 + threadIdx.x;     // 0..12287
    if (fid >= 12288) return;
    int lane = fid & 63;
    int ki   = (fid >> 6) % 3;
    int nt   = (fid / 192) & 7;
    int cell = (fid / 1536) & 3;
    int grp  = fid / 6144;
    const float* Wih = grp ? dWih : eWih;
    const float* Whh = grp ? dWhh : eWhh;
    int gate = nt * 16 + (lane & 15);
    int k0   = ki * 32 + (lane >> 4) * 8;
    size_t base = (size_t)grp * 98304 + (size_t)cell * 12288 + nt * 1536 + ki * 512 + lane * 8;
#pragma unroll
    for (int j = 0; j < 8; ++j) {
        int k = k0 + j;
        float v = (k < 64) ? Wih[(size_t)cell * 8192 + gate * 64 + k]
                           : Whh[(size_t)cell * 4096 + gate * 32 + (k - 64)];
        __hip_bfloat16 hi, lo; split_bf(v, hi, lo);
        ws[base + j]         = hi;
        ws[base + 49152 + j] = lo;
    }
}

// ---------------------------------------------------------------------------
// Encoder layer (both directions). 512 thr = 8 waves, 32 batch rows/block.
// wave w: dir d=w>>2, Mtile mt=(w>>1)&1, unit-half q=w&1.
// Job j (0..3) -> ntile 2j+q -> gate 32j + u  => lane holds i,f,g,o of unit u.
// ---------------------------------------------------------------------------
__global__ __launch_bounds__(512, 2)
void enc_kernel(const float* __restrict__ X,                 // layer0: x [B,T,64], else null
                const __hip_bfloat16* __restrict__ Xh,       // layer1: xs1 hi [T,B,64]
                const __hip_bfloat16* __restrict__ Xl,
                const float* __restrict__ h0, const float* __restrict__ c0,
                const __hip_bfloat16* __restrict__ Whi, const __hip_bfloat16* __restrict__ Wlo,
                const float* __restrict__ bias, int layer,
                __hip_bfloat16* __restrict__ outh, __hip_bfloat16* __restrict__ outl,
                float* __restrict__ z)
{
    __shared__ __hip_bfloat16 Yh[2][32][72], Yl[2][32][72];
    __shared__ __hip_bfloat16 Hh[2][32][40], Hl[2][32][40];

    const int tid = threadIdx.x, w = tid >> 6, lane = tid & 63;
    const int d = w >> 2, mt = (w >> 1) & 1, q = w & 1;
    const int n = lane & 15, kg = lane >> 4;
    const int u = q * 16 + n;
    const int row0 = blockIdx.x * 32;
    const int ci = 2 * layer + d;
    const int mrow = mt * 16 + kg * 4;   // rows for D regs / elementwise
    const int am   = mt * 16 + n;        // row for A-fragment loads

    // persistent weight fragments (96 VGPRs)
    bf8v Bh[4][3], Bl[4][3];
#pragma unroll
    for (int j = 0; j < 4; ++j)
#pragma unroll
        for (int ki = 0; ki < 3; ++ki) {
            size_t off = (size_t)d * 12288 + (2 * j + q) * 1536 + ki * 512 + lane * 8;
            Bh[j][ki] = *(const bf8v*)(Whi + off);
            Bl[j][ki] = *(const bf8v*)(Wlo + off);
        }
    float bj[4];
#pragma unroll
    for (int j = 0; j < 4; ++j) bj[j] = bias[d * 128 + 32 * j + u];

    float cst[4], h2[4];
#pragma unroll
    for (int r = 0; r < 4; ++r)
        cst[r] = c0[((size_t)ci * Bn + row0 + mrow + r) * Hn + u];

    for (int i = tid; i < 2 * 32 * 32; i += 512) {
        int dd = i >> 10, rr = (i >> 5) & 31, jj = i & 31;
        float v = h0[((size_t)(2 * layer + dd) * Bn + row0 + rr) * Hn + jj];
        split_bf(v, Hh[dd][rr][jj], Hl[dd][rr][jj]);
    }

    for (int t = 0; t < Tn; ++t) {
        // stage X tile for both directions
        {
            int sid = tid & 255, ds = tid >> 8;
            int tt = ds ? (Tn - 1 - t) : t;
            int rr = sid >> 3, cc0 = (sid & 7) * 8;
            if (X) {
                const float* src = X + ((size_t)(row0 + rr) * Tn + tt) * Fn + cc0;
#pragma unroll
                for (int e = 0; e < 8; ++e)
                    split_bf(src[e], Yh[ds][rr][cc0 + e], Yl[ds][rr][cc0 + e]);
            } else {
                size_t so = ((size_t)tt * Bn + row0 + rr) * Fn + cc0;
                *(bf8v*)&Yh[ds][rr][cc0] = *(const bf8v*)(Xh + so);
                *(bf8v*)&Yl[ds][rr][cc0] = *(const bf8v*)(Xl + so);
            }
        }
        __syncthreads();   // B1: Y staged, H current
        bf8v aH[3], aL[3];
        aH[0] = *(const bf8v*)&Yh[d][am][kg * 8];
        aL[0] = *(const bf8v*)&Yl[d][am][kg * 8];
        aH[1] = *(const bf8v*)&Yh[d][am][32 + kg * 8];
        aL[1] = *(const bf8v*)&Yl[d][am][32 + kg * 8];
        aH[2] = *(const bf8v*)&Hh[d][am][kg * 8];
        aL[2] = *(const bf8v*)&Hl[d][am][kg * 8];
        f4v acc[4];
#pragma unroll
        for (int j = 0; j < 4; ++j) acc[j] = (f4v){bj[j], bj[j], bj[j], bj[j]};
#pragma unroll
        for (int j = 0; j < 4; ++j)
#pragma unroll
            for (int ki = 0; ki < 3; ++ki) {
                acc[j] = mfma_bf16(aL[ki], Bh[j][ki], acc[j]);
                acc[j] = mfma_bf16(aH[ki], Bl[j][ki], acc[j]);
                acc[j] = mfma_bf16(aH[ki], Bh[j][ki], acc[j]);
            }
#pragma unroll
        for (int r = 0; r < 4; ++r) {
            float c2 = sigm(acc[1][r]) * cst[r] + sigm(acc[0][r]) * tanh_f(acc[2][r]);
            cst[r] = c2;
            h2[r] = sigm(acc[3][r]) * tanh_f(c2);
        }
        __syncthreads();   // B2: all fragment reads done
#pragma unroll
        for (int r = 0; r < 4; ++r)
            split_bf(h2[r], Hh[d][mrow + r][u], Hl[d][mrow + r][u]);
        if (outh) {
            __syncthreads();  // B3: H complete
            int a = tid >> 8, rem = tid & 255;
            int d2 = rem >> 7, rr = (rem >> 2) & 31, ch = rem & 3;
            int tp = d2 ? (Tn - 1 - t) : t;
            size_t doff = ((size_t)tp * Bn + row0 + rr) * Fn + d2 * 32 + ch * 8;
            const __hip_bfloat16* s = a ? &Hl[d2][rr][ch * 8] : &Hh[d2][rr][ch * 8];
            *(bf8v*)((a ? outl : outh) + doff) = *(const bf8v*)s;
        }
    }
#pragma unroll
    for (int r = 0; r < 4; ++r) {
        size_t zr = (size_t)(row0 + mrow + r) * 256;
        z[zr + ci * 32 + u]       = h2[r];
        z[zr + 128 + ci * 32 + u] = cst[r];
    }
}

// ---------------------------------------------------------------------------
// Decoder. Cells 0,1 (layer0) weights persistent in VGPRs; cells 2,3 in LDS.
// wave w: cA=w>>2 (and cB=2+cA), mt=(w>>1)&1, q=w&1.
// ---------------------------------------------------------------------------
__global__ __launch_bounds__(512, 2)
void dec_kernel(const __hip_bfloat16* __restrict__ Whi, const __hip_bfloat16* __restrict__ Wlo,
                const float* __restrict__ bias, const float* __restrict__ z,
                float* __restrict__ xhat)
{
    __shared__ __hip_bfloat16 WBh[2][8][3][64][8], WBl[2][8][3][64][8];  // cells 2,3
    __shared__ __hip_bfloat16 Yh[32][72], Yl[32][72];   // y feedback (layer0 input)
    __shared__ __hip_bfloat16 Mh[32][72], Ml[32][72];   // layer0 output (layer1 input)
    __shared__ __hip_bfloat16 Hh[4][32][40], Hl[4][32][40];
    __shared__ float ybuf[32][68];

    const int tid = threadIdx.x, w = tid >> 6, lane = tid & 63;
    const int cA = w >> 2, mt = (w >> 1) & 1, q = w & 1;
    const int n = lane & 15, kg = lane >> 4;
    const int u = q * 16 + n;
    const int row0 = blockIdx.x * 32;
    const int mrow = mt * 16 + kg * 4;
    const int am   = mt * 16 + n;

    // cells 2,3 fragments -> LDS (once)
    for (int i = tid; i < 3072; i += 512) {
        ((bf8v*)WBh)[i] = ((const bf8v*)Whi)[3072 + i];
        ((bf8v*)WBl)[i] = ((const bf8v*)Wlo)[3072 + i];
    }
    // cells 0,1 persistent fragments
    bf8v BhA[4][3], BlA[4][3];
#pragma unroll
    for (int j = 0; j < 4; ++j)
#pragma unroll
        for (int ki = 0; ki < 3; ++ki) {
            size_t off = (size_t)cA * 12288 + (2 * j + q) * 1536 + ki * 512 + lane * 8;
            BhA[j][ki] = *(const bf8v*)(Whi + off);
            BlA[j][ki] = *(const bf8v*)(Wlo + off);
        }
    float bA[4], bB[4];
#pragma unroll
    for (int j = 0; j < 4; ++j) {
        bA[j] = bias[cA * 128 + 32 * j + u];
        bB[j] = bias[(2 + cA) * 128 + 32 * j + u];
    }
    float cstA[4], cstB[4], hA[4], hB[4];
#pragma unroll
    for (int r = 0; r < 4; ++r) {
        size_t zr = (size_t)(row0 + mrow + r) * 256 + 128;
        cstA[r] = z[zr + cA * 32 + u];
        cstB[r] = z[zr + (2 + cA) * 32 + u];
    }
    for (int i = tid; i < 4 * 32 * 32; i += 512) {
        int cell = i >> 10, rr = (i >> 5) & 31, jj = i & 31;
        float v = z[(size_t)(row0 + rr) * 256 + cell * 32 + jj];
        split_bf(v, Hh[cell][rr][jj], Hl[cell][rr][jj]);
    }
    for (int i = tid; i < 2048; i += 512) {   // y0 = 0
        int rr = i >> 6, cc = i & 63;
        Yh[rr][cc] = __float2bfloat16(0.f);
        Yl[rr][cc] = __float2bfloat16(0.f);
    }

    for (int t = 0; t < Tn; ++t) {
        __syncthreads();   // B1: Y, H ready
        // ---- phase A: cells 0/1, V = [Y | H[cA]] ----
        bf8v aH[3], aL[3];
        aH[0] = *(const bf8v*)&Yh[am][kg * 8];
        aL[0] = *(const bf8v*)&Yl[am][kg * 8];
        aH[1] = *(const bf8v*)&Yh[am][32 + kg * 8];
        aL[1] = *(const bf8v*)&Yl[am][32 + kg * 8];
        aH[2] = *(const bf8v*)&Hh[cA][am][kg * 8];
        aL[2] = *(const bf8v*)&Hl[cA][am][kg * 8];
        f4v acc[4];
#pragma unroll
        for (int j = 0; j < 4; ++j) acc[j] = (f4v){bA[j], bA[j], bA[j], bA[j]};
#pragma unroll
        for (int j = 0; j < 4; ++j)
#pragma unroll
            for (int ki = 0; ki < 3; ++ki) {
                acc[j] = mfma_bf16(aL[ki], BhA[j][ki], acc[j]);
                acc[j] = mfma_bf16(aH[ki], BlA[j][ki], acc[j]);
                acc[j] = mfma_bf16(aH[ki], BhA[j][ki], acc[j]);
            }
#pragma unroll
        for (int r = 0; r < 4; ++r) {
            float c2 = sigm(acc[1][r]) * cstA[r] + sigm(acc[0][r]) * tanh_f(acc[2][r]);
            cstA[r] = c2;
            hA[r] = sigm(acc[3][r]) * tanh_f(c2);
        }
        __syncthreads();   // B2
#pragma unroll
        for (int r = 0; r < 4; ++r) {
            __hip_bfloat16 hi, lo; split_bf(hA[r], hi, lo);
            Hh[cA][mrow + r][u] = hi;           Hl[cA][mrow + r][u] = lo;
            Mh[mrow + r][cA * 32 + u] = hi;     Ml[mrow + r][cA * 32 + u] = lo;
        }
        __syncthreads();   // B3
        // ---- phase B: cells 2/3, V = [M | H[2+cA]] ----
        aH[0] = *(const bf8v*)&Mh[am][kg * 8];
        aL[0] = *(const bf8v*)&Ml[am][kg * 8];
        aH[1] = *(const bf8v*)&Mh[am][32 + kg * 8];
        aL[1] = *(const bf8v*)&Ml[am][32 + kg * 8];
        aH[2] = *(const bf8v*)&Hh[2 + cA][am][kg * 8];
        aL[2] = *(const bf8v*)&Hl[2 + cA][am][kg * 8];
#pragma unroll
        for (int j = 0; j < 4; ++j) acc[j] = (f4v){bB[j], bB[j], bB[j], bB[j]};
#pragma unroll
        for (int j = 0; j < 4; ++j)
#pragma unroll
            for (int ki = 0; ki < 3; ++ki) {
                bf8v bh = *(const bf8v*)&WBh[cA][2 * j + q][ki][lane][0];
                bf8v bl = *(const bf8v*)&WBl[cA][2 * j + q][ki][lane][0];
                acc[j] = mfma_bf16(aL[ki], bh, acc[j]);
                acc[j] = mfma_bf16(aH[ki], bl, acc[j]);
                acc[j] = mfma_bf16(aH[ki], bh, acc[j]);
            }
#pragma unroll
        for (int r = 0; r < 4; ++r) {
            float c2 = sigm(acc[1][r]) * cstB[r] + sigm(acc[0][r]) * tanh_f(acc[2][r]);
            cstB[r] = c2;
            hB[r] = sigm(acc[3][r]) * tanh_f(c2);
        }
        __syncthreads();   // B4
#pragma unroll
        for (int r = 0; r < 4; ++r) {
            __hip_bfloat16 hi, lo; split_bf(hB[r], hi, lo);
            Hh[2 + cA][mrow + r][u] = hi;   Hl[2 + cA][mrow + r][u] = lo;
            Yh[mrow + r][cA * 32 + u] = hi; Yl[mrow + r][cA * 32 + u] = lo;
            ybuf[mrow + r][cA * 32 + u] = hB[r];
        }
        __syncthreads();   // B5
        {
            int rr = tid >> 4, cc = (tid & 15) * 4;
            float4 v = *(const float4*)&ybuf[rr][cc];
            *(float4*)(xhat + ((size_t)(row0 + rr) * Tn + t) * Fn + cc) = v;
        }
    }
}

extern "C" void kernel_launch(void* const* d_in, const int* in_sizes, int n_in,
                              void* d_out, int out_size, void* d_ws, size_t ws_size,
                              hipStream_t stream) {
    const float* x    = (const float*)d_in[0];
    const float* h0   = (const float*)d_in[1];
    const float* c0   = (const float*)d_in[2];
    const float* eWih = (const float*)d_in[3];
    const float* eWhh = (const float*)d_in[4];
    const float* eb   = (const float*)d_in[5];
    const float* dWih = (const float*)d_in[6];
    const float* dWhh = (const float*)d_in[7];
    const float* db   = (const float*)d_in[8];

    float* out = (float*)d_out;
    __hip_bfloat16* xs1h = (__hip_bfloat16*)d_out;            // [T,B,64] bf16 hi
    __hip_bfloat16* xs1l = xs1h + (size_t)XHAT_ELEMS;         // [T,B,64] bf16 lo
    float* zb = out + (size_t)XHAT_ELEMS;                     // [B,256]
    __hip_bfloat16* wsb = (__hip_bfloat16*)d_ws;              // 196608 bf16 = 384 KB

    hipLaunchKernelGGL(prep_kernel, dim3(48), dim3(256), 0, stream,
                       eWih, eWhh, dWih, dWhh, wsb);
    // encoder layer 0
    hipLaunchKernelGGL(enc_kernel, dim3(256), dim3(512), 0, stream,
                       x, (const __hip_bfloat16*)nullptr, (const __hip_bfloat16*)nullptr,
                       h0, c0, wsb, wsb + 49152, eb, 0, xs1h, xs1l, zb);
    // encoder layer 1
    hipLaunchKernelGGL(enc_kernel, dim3(256), dim3(512), 0, stream,
                       (const float*)nullptr, xs1h, xs1l,
                       h0, c0, wsb + 24576, wsb + 49152 + 24576, eb + 256, 1,
                       (__hip_bfloat16*)nullptr, (__hip_bfloat16*)nullptr, zb);
    // decoder (overwrites xs1 region with fp32 x_hat)
    hipLaunchKernelGGL(dec_kernel, dim3(256), dim3(512), 0, stream,
                       wsb + 98304, wsb + 147456, db, zb, out);
}

// Round 3
// 447.025 us; speedup vs baseline: 88.4072x; 1.0852x over previous
//
#include <hip/hip_runtime.h>
#include <cstddef>
#include <cstdint>

#define Tn 52
#define Fn 64
#define Hn 32
#define Bn 8192
#define XHAT_ELEMS (Bn * Tn * Fn)   // fp32 elems of x_hat == 2 bf16 [T,B,64] arrays

typedef __attribute__((ext_vector_type(8))) short bf8v;   // 8 bf16 (4 VGPRs)
typedef __attribute__((ext_vector_type(4))) float f4v;    // 4 fp32 accum

__device__ __forceinline__ float sigm(float x)  { return 1.f / (1.f + __expf(-x)); }
__device__ __forceinline__ float tanh_f(float x){ return 1.f - 2.f / (__expf(2.f * x) + 1.f); }

__device__ __forceinline__ f4v mfma_bf16(bf8v a, bf8v b, f4v c) {
    return __builtin_amdgcn_mfma_f32_16x16x32_bf16(a, b, c, 0, 0, 0);
}

// truncation split: v = hi + lo + O(2^-16 |v|); tail captured exactly in lo
__device__ __forceinline__ void split_tr(float v, unsigned short& hi, unsigned short& lo) {
    unsigned b = __float_as_uint(v);
    hi = (unsigned short)(b >> 16);
    float lf = v - __uint_as_float(b & 0xFFFF0000u);
    lo = (unsigned short)(__float_as_uint(lf) >> 16);
}

__device__ __forceinline__ void split8(float4 a, float4 b, bf8v& h, bf8v& l) {
    float v[8] = {a.x, a.y, a.z, a.w, b.x, b.y, b.z, b.w};
#pragma unroll
    for (int j = 0; j < 8; ++j) {
        unsigned bb = __float_as_uint(v[j]);
        h[j] = (short)(bb >> 16);
        float lf = v[j] - __uint_as_float(bb & 0xFFFF0000u);
        l[j] = (short)(__float_as_uint(lf) >> 16);
    }
}

__device__ __forceinline__ void lstm_update(const f4v* acc, float* cst, float* h) {
#pragma unroll
    for (int r = 0; r < 4; ++r) {
        float c2 = sigm(acc[1][r]) * cst[r] + sigm(acc[0][r]) * tanh_f(acc[2][r]);
        cst[r] = c2;
        h[r] = sigm(acc[3][r]) * tanh_f(c2);
    }
}

// 3-product bf16 split GEMM step: acc += aL*Bh + aH*Bl + aH*Bh
#define GM(ki, WH, WL)                                            \
    { _Pragma("unroll") for (int j = 0; j < 4; ++j) {             \
        acc[j] = mfma_bf16(fl, WH[j][ki], acc[j]);                \
        acc[j] = mfma_bf16(fh, WL[j][ki], acc[j]);                \
        acc[j] = mfma_bf16(fh, WH[j][ki], acc[j]); } }

// ---------------------------------------------------------------------------
// Prep: weights -> fragment-ordered bf16 hi/lo in ws.
// [grp(enc,dec)][cell(4)][ntile(8)][kiter(3)][lane(64)][j(8)]
//   gate = nt*16 + (lane&15); k = ki*32 + (lane>>4)*8 + j
//   k<64 -> Wih[cell][gate][k], else Whh[cell][gate][k-64]
// hi at grp*98304; lo at +49152 within group.
// ---------------------------------------------------------------------------
__global__ void prep_kernel(const float* __restrict__ eWih, const float* __restrict__ eWhh,
                            const float* __restrict__ dWih, const float* __restrict__ dWhh,
                            unsigned short* __restrict__ ws)
{
    int fid = blockIdx.x * 256 + threadIdx.x;
    if (fid >= 12288) return;
    int lane = fid & 63;
    int ki   = (fid >> 6) % 3;
    int nt   = (fid / 192) & 7;
    int cell = (fid / 1536) & 3;
    int grp  = fid / 6144;
    const float* Wih = grp ? dWih : eWih;
    const float* Whh = grp ? dWhh : eWhh;
    int gate = nt * 16 + (lane & 15);
    int k0   = ki * 32 + (lane >> 4) * 8;
    size_t base = (size_t)grp * 98304 + (size_t)cell * 12288 + nt * 1536 + ki * 512 + lane * 8;
#pragma unroll
    for (int j = 0; j < 8; ++j) {
        int k = k0 + j;
        float v = (k < 64) ? Wih[(size_t)cell * 8192 + gate * 64 + k]
                           : Whh[(size_t)cell * 4096 + gate * 32 + (k - 64)];
        split_tr(v, ws[base + j], ws[base + 49152 + j]);
    }
}

// ---------------------------------------------------------------------------
// Encoder layer: block = 128 thr (2 waves, q-halves), 16 rows, ONE direction.
// grid (512, 2). Weights in VGPRs; x prefetched from global; 1 barrier/step.
// ---------------------------------------------------------------------------
template<int IS_L0>
__global__ __launch_bounds__(128, 2)
void enc_kernel(const float* __restrict__ X,                  // layer0 x [B,T,64]
                const unsigned short* __restrict__ Xh,        // layer1 xs1 hi [T,B,64]
                const unsigned short* __restrict__ Xl,
                const float* __restrict__ h0, const float* __restrict__ c0,
                const unsigned short* __restrict__ Whi, const unsigned short* __restrict__ Wlo,
                const float* __restrict__ bias, int layer,
                unsigned short* __restrict__ outh, unsigned short* __restrict__ outl,
                float* __restrict__ z)
{
    __shared__ unsigned short Hh[2][16][40], Hl[2][16][40];
    const int tid = threadIdx.x, q = tid >> 6, lane = tid & 63;
    const int n = lane & 15, kg = lane >> 4, u = q * 16 + n;
    const int row0 = blockIdx.x * 16, d = blockIdx.y, ci = 2 * layer + d;
    const int row = row0 + n;   // A-fragment row for this lane

    // persistent weight fragments: 24 bf8v = 96 VGPR
    bf8v Wh_[4][3], Wl_[4][3];
#pragma unroll
    for (int j = 0; j < 4; ++j)
#pragma unroll
        for (int ki = 0; ki < 3; ++ki) {
            size_t off = (size_t)d * 12288 + (2 * j + q) * 1536 + ki * 512 + lane * 8;
            Wh_[j][ki] = *(const bf8v*)(Whi + off);
            Wl_[j][ki] = *(const bf8v*)(Wlo + off);
        }
    float bj[4];
#pragma unroll
    for (int j = 0; j < 4; ++j) bj[j] = bias[d * 128 + 32 * j + u];
    float cst[4], h2[4];
#pragma unroll
    for (int r = 0; r < 4; ++r)
        cst[r] = c0[((size_t)ci * Bn + row0 + kg * 4 + r) * Hn + u];

    {   // h0 -> LDS buffer 0 (16 rows x 32 units), 4 elems/thread
        int rr = tid >> 3, jj = (tid & 7) * 4;
        const float* src = h0 + ((size_t)ci * Bn + row0 + rr) * Hn + jj;
#pragma unroll
        for (int e = 0; e < 4; ++e)
            split_tr(src[e], Hh[0][rr][jj + e], Hl[0][rr][jj + e]);
    }
    __syncthreads();

    int cur = 0;
    // prefetch t = 0
    float4 pa0, pa1, pb0, pb1;
    bf8v ph0, pl0, ph1, pl1;
    {
        int tt = d ? (Tn - 1) : 0;
        if (IS_L0) {
            const float4* xp = (const float4*)(X + (size_t)row * (Tn * Fn) + (size_t)tt * Fn + kg * 8);
            pa0 = xp[0]; pa1 = xp[1]; pb0 = xp[8]; pb1 = xp[9];
        } else {
            size_t so = ((size_t)tt * Bn + row) * Fn + kg * 8;
            ph0 = *(const bf8v*)(Xh + so);      pl0 = *(const bf8v*)(Xl + so);
            ph1 = *(const bf8v*)(Xh + so + 32); pl1 = *(const bf8v*)(Xl + so + 32);
        }
    }

    for (int t = 0; t < Tn; ++t) {
        const int nxt = cur ^ 1;
        // consume prefetched x into ki0/ki1 fragments
        bf8v ah0, al0, ah1, al1;
        if (IS_L0) { split8(pa0, pa1, ah0, al0); split8(pb0, pb1, ah1, al1); }
        else       { ah0 = ph0; al0 = pl0; ah1 = ph1; al1 = pl1; }
        // issue prefetch for t+1 (covered by this step's compute)
        {
            int tn = (t + 1 < Tn) ? t + 1 : t;
            int ttn = d ? (Tn - 1 - tn) : tn;
            if (IS_L0) {
                const float4* xp = (const float4*)(X + (size_t)row * (Tn * Fn) + (size_t)ttn * Fn + kg * 8);
                pa0 = xp[0]; pa1 = xp[1]; pb0 = xp[8]; pb1 = xp[9];
            } else {
                size_t so = ((size_t)ttn * Bn + row) * Fn + kg * 8;
                ph0 = *(const bf8v*)(Xh + so);      pl0 = *(const bf8v*)(Xl + so);
                ph1 = *(const bf8v*)(Xh + so + 32); pl1 = *(const bf8v*)(Xl + so + 32);
            }
        }
        f4v acc[4];
#pragma unroll
        for (int j = 0; j < 4; ++j) acc[j] = (f4v){bj[j], bj[j], bj[j], bj[j]};
        { bf8v fh = ah0, fl = al0; GM(0, Wh_, Wl_); }
        { bf8v fh = ah1, fl = al1; GM(1, Wh_, Wl_); }
        { bf8v fh = *(const bf8v*)&Hh[cur][n][kg * 8];
          bf8v fl = *(const bf8v*)&Hl[cur][n][kg * 8]; GM(2, Wh_, Wl_); }
        lstm_update(acc, cst, h2);
#pragma unroll
        for (int r = 0; r < 4; ++r)
            split_tr(h2[r], Hh[nxt][kg * 4 + r][u], Hl[nxt][kg * 4 + r][u]);
        __syncthreads();   // the ONE barrier: H[nxt] complete; H[cur] reads done
        if (IS_L0) {       // coalesced xs1 store: 128 thr x 16B = 2 KB
            int a = tid >> 6, rr = (tid >> 2) & 15, ch = tid & 3;
            int tp = d ? (Tn - 1 - t) : t;
            const unsigned short* s = a ? &Hl[nxt][rr][ch * 8] : &Hh[nxt][rr][ch * 8];
            *(bf8v*)((a ? outl : outh) + ((size_t)tp * Bn + row0 + rr) * Fn + d * 32 + ch * 8)
                = *(const bf8v*)s;
        }
        cur ^= 1;
    }
#pragma unroll
    for (int r = 0; r < 4; ++r) {
        size_t zr = (size_t)(row0 + kg * 4 + r) * 256;
        z[zr + ci * 32 + u]       = h2[r];
        z[zr + 128 + ci * 32 + u] = cst[r];
    }
}

// ---------------------------------------------------------------------------
// Decoder: block = 256 thr (4 waves: cA in {0,1} x q), 16 rows, grid 512.
// ALL weights (phase A + B) in VGPRs; LDS only for y/m/h exchange; 2 barriers/step.
// ---------------------------------------------------------------------------
__global__ __launch_bounds__(256, 2)
void dec_kernel(const unsigned short* __restrict__ Whi, const unsigned short* __restrict__ Wlo,
                const float* __restrict__ bias, const float* __restrict__ z,
                float* __restrict__ xhat)
{
    __shared__ unsigned short Yh[2][16][72], Yl[2][16][72];
    __shared__ unsigned short Mh[16][72],    Ml[16][72];
    __shared__ unsigned short Hh[4][2][16][40], Hl[4][2][16][40];

    const int tid = threadIdx.x, w = tid >> 6, lane = tid & 63;
    const int cA = w >> 1, q = w & 1, cB = 2 + cA;
    const int n = lane & 15, kg = lane >> 4, u = q * 16 + n;
    const int row0 = blockIdx.x * 16;

    // weights: 48 bf8v = 192 VGPR (phase A cell cA + phase B cell cB, q-half)
    bf8v WAh[4][3], WAl[4][3], WBh[4][3], WBl[4][3];
#pragma unroll
    for (int j = 0; j < 4; ++j)
#pragma unroll
        for (int ki = 0; ki < 3; ++ki) {
            size_t oA = (size_t)cA * 12288 + (2 * j + q) * 1536 + ki * 512 + lane * 8;
            size_t oB = (size_t)cB * 12288 + (2 * j + q) * 1536 + ki * 512 + lane * 8;
            WAh[j][ki] = *(const bf8v*)(Whi + oA);
            WAl[j][ki] = *(const bf8v*)(Wlo + oA);
            WBh[j][ki] = *(const bf8v*)(Whi + oB);
            WBl[j][ki] = *(const bf8v*)(Wlo + oB);
        }
    float bA[4], bB[4];
#pragma unroll
    for (int j = 0; j < 4; ++j) {
        bA[j] = bias[cA * 128 + 32 * j + u];
        bB[j] = bias[cB * 128 + 32 * j + u];
    }
    float cstA[4], cstB[4], hA[4], hB[4];
#pragma unroll
    for (int r = 0; r < 4; ++r) {
        size_t zr = (size_t)(row0 + kg * 4 + r) * 256 + 128;
        cstA[r] = z[zr + cA * 32 + u];
        cstB[r] = z[zr + cB * 32 + u];
    }
    {   // h-states (4 cells x 16 rows x 32) -> LDS buffer 0; 8 elems/thread
        int cell = tid >> 6, rr = (tid >> 2) & 15, jj = (tid & 3) * 8;
        const float* src = z + (size_t)(row0 + rr) * 256 + cell * 32 + jj;
#pragma unroll
        for (int e = 0; e < 8; ++e)
            split_tr(src[e], Hh[cell][0][rr][jj + e], Hl[cell][0][rr][jj + e]);
    }
    {   // y0 = 0
        unsigned short* yh = &Yh[0][0][0];
        unsigned short* yl = &Yl[0][0][0];
        for (int i = tid; i < 16 * 72; i += 256) { yh[i] = 0; yl[i] = 0; }
    }
    __syncthreads();

    int cur = 0;
    for (int t = 0; t < Tn; ++t) {
        const int nxt = cur ^ 1;
        // ---- phase A: cells 0/1, V = [y | h[cA]] ----
        f4v acc[4];
#pragma unroll
        for (int j = 0; j < 4; ++j) acc[j] = (f4v){bA[j], bA[j], bA[j], bA[j]};
        { bf8v fh = *(const bf8v*)&Yh[cur][n][kg * 8];
          bf8v fl = *(const bf8v*)&Yl[cur][n][kg * 8];          GM(0, WAh, WAl); }
        { bf8v fh = *(const bf8v*)&Yh[cur][n][32 + kg * 8];
          bf8v fl = *(const bf8v*)&Yl[cur][n][32 + kg * 8];     GM(1, WAh, WAl); }
        { bf8v fh = *(const bf8v*)&Hh[cA][cur][n][kg * 8];
          bf8v fl = *(const bf8v*)&Hl[cA][cur][n][kg * 8];      GM(2, WAh, WAl); }
        lstm_update(acc, cstA, hA);
#pragma unroll
        for (int r = 0; r < 4; ++r) {
            unsigned short hi, lo; split_tr(hA[r], hi, lo);
            Mh[kg * 4 + r][cA * 32 + u] = hi;  Ml[kg * 4 + r][cA * 32 + u] = lo;
            Hh[cA][nxt][kg * 4 + r][u] = hi;   Hl[cA][nxt][kg * 4 + r][u] = lo;
        }
        __syncthreads();   // B1: m visible; y/h[cA] reads done
        // ---- phase B: cells 2/3, V = [m | h[cB]] ----
#pragma unroll
        for (int j = 0; j < 4; ++j) acc[j] = (f4v){bB[j], bB[j], bB[j], bB[j]};
        { bf8v fh = *(const bf8v*)&Mh[n][kg * 8];
          bf8v fl = *(const bf8v*)&Ml[n][kg * 8];               GM(0, WBh, WBl); }
        { bf8v fh = *(const bf8v*)&Mh[n][32 + kg * 8];
          bf8v fl = *(const bf8v*)&Ml[n][32 + kg * 8];          GM(1, WBh, WBl); }
        { bf8v fh = *(const bf8v*)&Hh[cB][cur][n][kg * 8];
          bf8v fl = *(const bf8v*)&Hl[cB][cur][n][kg * 8];      GM(2, WBh, WBl); }
        lstm_update(acc, cstB, hB);
#pragma unroll
        for (int r = 0; r < 4; ++r) {
            unsigned short hi, lo; split_tr(hB[r], hi, lo);
            Yh[nxt][kg * 4 + r][cA * 32 + u] = hi;  Yl[nxt][kg * 4 + r][cA * 32 + u] = lo;
            Hh[cB][nxt][kg * 4 + r][u] = hi;        Hl[cB][nxt][kg * 4 + r][u] = lo;
            xhat[((size_t)(row0 + kg * 4 + r) * Tn + t) * Fn + cA * 32 + u] = hB[r];
        }
        __syncthreads();   // B2: y[nxt]/h[nxt] visible; m reads done
        cur ^= 1;
    }
}

extern "C" void kernel_launch(void* const* d_in, const int* in_sizes, int n_in,
                              void* d_out, int out_size, void* d_ws, size_t ws_size,
                              hipStream_t stream) {
    const float* x    = (const float*)d_in[0];
    const float* h0   = (const float*)d_in[1];
    const float* c0   = (const float*)d_in[2];
    const float* eWih = (const float*)d_in[3];
    const float* eWhh = (const float*)d_in[4];
    const float* eb   = (const float*)d_in[5];
    const float* dWih = (const float*)d_in[6];
    const float* dWhh = (const float*)d_in[7];
    const float* db   = (const float*)d_in[8];

    float* out = (float*)d_out;
    unsigned short* xs1h = (unsigned short*)d_out;            // [T,B,64] bf16 hi
    unsigned short* xs1l = xs1h + (size_t)XHAT_ELEMS;         // [T,B,64] bf16 lo
    float* zb = out + (size_t)XHAT_ELEMS;                     // [B,256] latent
    unsigned short* wsb = (unsigned short*)d_ws;              // 384 KB fragments

    hipLaunchKernelGGL(prep_kernel, dim3(48), dim3(256), 0, stream,
                       eWih, eWhh, dWih, dWhh, wsb);
    // encoder layer 0: x -> xs1 (hi/lo) + z slots 0,1
    hipLaunchKernelGGL((enc_kernel<1>), dim3(Bn / 16, 2), dim3(128), 0, stream,
                       x, (const unsigned short*)nullptr, (const unsigned short*)nullptr,
                       h0, c0, wsb, wsb + 49152, eb, 0, xs1h, xs1l, zb);
    // encoder layer 1: xs1 -> z slots 2,3
    hipLaunchKernelGGL((enc_kernel<0>), dim3(Bn / 16, 2), dim3(128), 0, stream,
                       (const float*)nullptr, xs1h, xs1l,
                       h0, c0, wsb + 24576, wsb + 49152 + 24576, eb + 256, 1,
                       (unsigned short*)nullptr, (unsigned short*)nullptr, zb);
    // decoder: z -> x_hat (overwrites xs1 region)
    hipLaunchKernelGGL(dec_kernel, dim3(Bn / 16), dim3(256), 0, stream,
                       wsb + 98304, wsb + 147456, db, zb, out);
}

// Round 4
// 404.742 us; speedup vs baseline: 97.6431x; 1.1045x over previous
//
#include <hip/hip_runtime.h>
#include <cstddef>
#include <cstdint>

#define Tn 52
#define Fn 64
#define Hn 32
#define Bn 8192
#define XHAT_ELEMS (Bn * Tn * Fn)   // fp32 elems of x_hat == 2 bf16 [T,B,64] arrays
#define L2E 1.44269504088896340736f

typedef __attribute__((ext_vector_type(8))) short bf8v;   // 8 bf16 (4 VGPRs)
typedef __attribute__((ext_vector_type(4))) float f4v;    // 4 fp32 accum

__device__ __forceinline__ f4v mfma_bf16(bf8v a, bf8v b, f4v c) {
    return __builtin_amdgcn_mfma_f32_16x16x32_bf16(a, b, c, 0, 0, 0);
}

// truncation split: v = hi + lo + O(2^-17 |v|)
__device__ __forceinline__ void split_tr(float v, unsigned short& hi, unsigned short& lo) {
    unsigned b = __float_as_uint(v);
    hi = (unsigned short)(b >> 16);
    float lf = v - __uint_as_float(b & 0xFFFF0000u);
    lo = (unsigned short)(__float_as_uint(lf) >> 16);
}

__device__ __forceinline__ void split8v(float4 a, float4 b, bf8v& h, bf8v& l) {
    float v[8] = {a.x, a.y, a.z, a.w, b.x, b.y, b.z, b.w};
#pragma unroll
    for (int j = 0; j < 8; ++j) {
        unsigned bb = __float_as_uint(v[j]);
        h[j] = (short)(bb >> 16);
        float lf = v[j] - __uint_as_float(bb & 0xFFFF0000u);
        l[j] = (short)(__float_as_uint(lf) >> 16);
    }
}

// barrier WITHOUT vmcnt drain: all cross-thread data flows via LDS; global
// prefetch loads / output stores may stay in flight across it.
__device__ __forceinline__ void lds_barrier() {
    __builtin_amdgcn_sched_barrier(0);
    asm volatile("s_waitcnt lgkmcnt(0)" ::: "memory");
    __builtin_amdgcn_s_barrier();
    __builtin_amdgcn_sched_barrier(0);
}

// Gate pre-activations are pre-scaled: i,f,o rows by log2e, g rows by 2*log2e.
// sigm(a) = 1/(1+2^-a'), tanh(g) = (1-2^-g')/(1+2^-g').  Merged divisions:
// c2 = [c*(1+ei)(1+eg) + (1-eg)(1+ef)] / [(1+ef)(1+ei)(1+eg)]   (one rcp)
// h  = (1-e2) / [(1+eo)(1+e2)]                                   (one rcp)
// Clamp exp2 args at 40 (2^40 products stay finite; sigmoid(<-27) == 0).
__device__ __forceinline__ float lstm_one(float aI, float aF, float aG, float aO, float& cst) {
    float ei = exp2f(fminf(40.f, -aI));
    float ef = exp2f(fminf(40.f, -aF));
    float eg = exp2f(fminf(40.f, -aG));
    float eo = exp2f(fminf(40.f, -aO));
    float p   = (1.f + ei) * (1.f + eg);
    float num = cst * p + (1.f - eg) * (1.f + ef);
    float den = (1.f + ef) * p;
    float c2  = num * __builtin_amdgcn_rcpf(den);
    cst = c2;
    float e2 = exp2f(fminf(40.f, -2.f * L2E * c2));
    return (1.f - e2) * __builtin_amdgcn_rcpf((1.f + eo) * (1.f + e2));
}

// 3-product bf16 split: acc += aL*Wh + aH*Wl + aH*Wh
#define GM3(ACC, AH, AL, WH_, WL_)     \
    ACC = mfma_bf16(AL, WH_, ACC);     \
    ACC = mfma_bf16(AH, WL_, ACC);     \
    ACC = mfma_bf16(AH, WH_, ACC);

// ---------------------------------------------------------------------------
// Prep: weights -> fragment-ordered bf16 hi/lo in ws, PRE-SCALED by log2e
// (g-gate rows by 2*log2e).  Layout: [grp][cell(4)][nt(8)][ki(3)][lane(64)][j(8)]
//   gate = nt*16 + (lane&15); k = ki*32 + (lane>>4)*8 + j
//   k<64 -> Wih[cell][gate][k], else Whh[cell][gate][k-64]
// ---------------------------------------------------------------------------
__global__ void prep_kernel(const float* __restrict__ eWih, const float* __restrict__ eWhh,
                            const float* __restrict__ dWih, const float* __restrict__ dWhh,
                            unsigned short* __restrict__ ws)
{
    int fid = blockIdx.x * 256 + threadIdx.x;
    if (fid >= 12288) return;
    int lane = fid & 63;
    int ki   = (fid >> 6) % 3;
    int nt   = (fid / 192) & 7;
    int cell = (fid / 1536) & 3;
    int grp  = fid / 6144;
    const float* Wih = grp ? dWih : eWih;
    const float* Whh = grp ? dWhh : eWhh;
    int gate = nt * 16 + (lane & 15);
    float scale = ((gate >> 5) == 2) ? 2.f * L2E : L2E;   // g-gate rows [64,96)
    int k0 = ki * 32 + (lane >> 4) * 8;
    size_t base = (size_t)grp * 98304 + (size_t)cell * 12288 + nt * 1536 + ki * 512 + lane * 8;
#pragma unroll
    for (int j = 0; j < 8; ++j) {
        int k = k0 + j;
        float v = (k < 64) ? Wih[(size_t)cell * 8192 + gate * 64 + k]
                           : Whh[(size_t)cell * 4096 + gate * 32 + (k - 64)];
        v *= scale;
        split_tr(v, ws[base + j], ws[base + 49152 + j]);
    }
}

// ---------------------------------------------------------------------------
// Encoder layer: block = 512 thr (8 waves), 32 rows, BOTH directions. grid 256.
// Compute role: wave (wd = dir, g = gate-type) -> 36 MFMA into gbuf.
// Combine role: lane (cd, cu, rg) -> 4 LSTM instances (all 512 lanes do trans).
// ---------------------------------------------------------------------------
template<int IS_L0>
__global__ __launch_bounds__(512, 2)
void enc_kernel(const float* __restrict__ X,                  // layer0: x [B,T,64]
                const unsigned short* __restrict__ Xg_h,      // layer1: xs1 hi [T,B,64]
                const unsigned short* __restrict__ Xg_l,
                const float* __restrict__ h0, const float* __restrict__ c0,
                const unsigned short* __restrict__ Whi, const unsigned short* __restrict__ Wlo,
                const float* __restrict__ bias, int layer,
                unsigned short* __restrict__ outh, unsigned short* __restrict__ outl,
                float* __restrict__ z)
{
    __shared__ __align__(16) float gbuf[2][4][32][36];                 // [dir][gt][unit][row]
    __shared__ __align__(16) unsigned short Xbh[2][2][32][72], Xbl[2][2][32][72]; // [buf][dir]
    __shared__ __align__(16) unsigned short Hh[2][32][40], Hl[2][32][40];

    const int tid = threadIdx.x, w = tid >> 6, lane = tid & 63;
    const int wd = w >> 2, g = w & 3;
    const int n16 = lane & 15, kg = lane >> 4;
    const int row0 = blockIdx.x * 32;
    const int cd = tid >> 8, cu = tid & 31, rg = (tid >> 5) & 7;   // combine role
    const int sd = tid >> 8, srow = (tid >> 3) & 31, sc8 = (tid & 7) * 8;  // stage role

    bf8v WH[2][3], WL[2][3];
#pragma unroll
    for (int s = 0; s < 2; ++s)
#pragma unroll
        for (int ki = 0; ki < 3; ++ki) {
            size_t off = (size_t)wd * 12288 + (g * 2 + s) * 1536 + ki * 512 + lane * 8;
            WH[s][ki] = *(const bf8v*)(Whi + off);
            WL[s][ki] = *(const bf8v*)(Wlo + off);
        }
    const float bscale = (g == 2) ? 2.f * L2E : L2E;
    float bs[2];
#pragma unroll
    for (int s = 0; s < 2; ++s)
        bs[s] = bias[wd * 128 + (g * 2 + s) * 16 + n16] * bscale;

    const int ci_c = 2 * layer + cd;
    float cst[4], hfin[4];
#pragma unroll
    for (int j = 0; j < 4; ++j)
        cst[j] = c0[((size_t)ci_c * Bn + row0 + 4 * rg + j) * Hn + cu];

    {   // h0 -> H (split): 2*32*32/512 = 4 elems/thread
        int hd = tid >> 8, hrow = (tid >> 3) & 31, c4 = (tid & 7) * 4;
        const float* src = h0 + ((size_t)(2 * layer + hd) * Bn + row0 + hrow) * Hn + c4;
#pragma unroll
        for (int e = 0; e < 4; ++e)
            split_tr(src[e], Hh[hd][hrow][c4 + e], Hl[hd][hrow][c4 + e]);
    }

    // stage t=0, prefetch t=1
    float4 pf0, pf1; bf8v pgh, pgl;
    {
        int tt0 = sd ? (Tn - 1) : 0;
        if (IS_L0) {
            const float* sp = X + ((size_t)(row0 + srow) * Tn + tt0) * Fn + sc8;
            bf8v h_, l_;
            split8v(*(const float4*)sp, *(const float4*)(sp + 4), h_, l_);
            *(bf8v*)&Xbh[0][sd][srow][sc8] = h_;
            *(bf8v*)&Xbl[0][sd][srow][sc8] = l_;
        } else {
            size_t so = ((size_t)tt0 * Bn + row0 + srow) * Fn + sc8;
            *(bf8v*)&Xbh[0][sd][srow][sc8] = *(const bf8v*)(Xg_h + so);
            *(bf8v*)&Xbl[0][sd][srow][sc8] = *(const bf8v*)(Xg_l + so);
        }
        int tt1 = sd ? (Tn - 2) : 1;
        if (IS_L0) {
            const float* sp = X + ((size_t)(row0 + srow) * Tn + tt1) * Fn + sc8;
            pf0 = *(const float4*)sp; pf1 = *(const float4*)(sp + 4);
        } else {
            size_t so = ((size_t)tt1 * Bn + row0 + srow) * Fn + sc8;
            pgh = *(const bf8v*)(Xg_h + so); pgl = *(const bf8v*)(Xg_l + so);
        }
    }
    lds_barrier();

    for (int t = 0; t < Tn; ++t) {
        const int cur = t & 1;
        // ---- compute: gate pre-activations -> gbuf ----
        bf8v aH[2][3], aL[2][3];
#pragma unroll
        for (int mt = 0; mt < 2; ++mt) {
            int r = mt * 16 + n16;
            aH[mt][0] = *(const bf8v*)&Xbh[cur][wd][r][kg * 8];
            aL[mt][0] = *(const bf8v*)&Xbl[cur][wd][r][kg * 8];
            aH[mt][1] = *(const bf8v*)&Xbh[cur][wd][r][32 + kg * 8];
            aL[mt][1] = *(const bf8v*)&Xbl[cur][wd][r][32 + kg * 8];
            aH[mt][2] = *(const bf8v*)&Hh[wd][r][kg * 8];
            aL[mt][2] = *(const bf8v*)&Hl[wd][r][kg * 8];
        }
        f4v acc[2][2];
#pragma unroll
        for (int mt = 0; mt < 2; ++mt)
#pragma unroll
            for (int s = 0; s < 2; ++s)
                acc[mt][s] = (f4v){bs[s], bs[s], bs[s], bs[s]};
#pragma unroll
        for (int ki = 0; ki < 3; ++ki)
#pragma unroll
            for (int mt = 0; mt < 2; ++mt)
#pragma unroll
                for (int s = 0; s < 2; ++s) {
                    GM3(acc[mt][s], aH[mt][ki], aL[mt][ki], WH[s][ki], WL[s][ki]);
                }
#pragma unroll
        for (int mt = 0; mt < 2; ++mt)
#pragma unroll
            for (int s = 0; s < 2; ++s)
                *(f4v*)&gbuf[wd][g][s * 16 + n16][mt * 16 + kg * 4] = acc[mt][s];
        lds_barrier();
        // ---- combine + stage next X ----
        if (t + 1 < Tn) {
            if (IS_L0) {
                bf8v h_, l_; split8v(pf0, pf1, h_, l_);
                *(bf8v*)&Xbh[cur ^ 1][sd][srow][sc8] = h_;
                *(bf8v*)&Xbl[cur ^ 1][sd][srow][sc8] = l_;
            } else {
                *(bf8v*)&Xbh[cur ^ 1][sd][srow][sc8] = pgh;
                *(bf8v*)&Xbl[cur ^ 1][sd][srow][sc8] = pgl;
            }
        }
        {   // issue loads for t+2 (latency hidden across a full step)
            int ts = (t + 2 < Tn) ? t + 2 : Tn - 1;
            int tt = sd ? (Tn - 1 - ts) : ts;
            if (IS_L0) {
                const float* sp = X + ((size_t)(row0 + srow) * Tn + tt) * Fn + sc8;
                pf0 = *(const float4*)sp; pf1 = *(const float4*)(sp + 4);
            } else {
                size_t so = ((size_t)tt * Bn + row0 + srow) * Fn + sc8;
                pgh = *(const bf8v*)(Xg_h + so); pgl = *(const bf8v*)(Xg_l + so);
            }
        }
        f4v gI = *(const f4v*)&gbuf[cd][0][cu][rg * 4];
        f4v gF = *(const f4v*)&gbuf[cd][1][cu][rg * 4];
        f4v gG = *(const f4v*)&gbuf[cd][2][cu][rg * 4];
        f4v gO = *(const f4v*)&gbuf[cd][3][cu][rg * 4];
        int tp = cd ? (Tn - 1 - t) : t;
#pragma unroll
        for (int j = 0; j < 4; ++j) {
            float h = lstm_one(gI[j], gF[j], gG[j], gO[j], cst[j]);
            hfin[j] = h;
            unsigned short hi_, lo_;
            split_tr(h, hi_, lo_);
            Hh[cd][4 * rg + j][cu] = hi_;
            Hl[cd][4 * rg + j][cu] = lo_;
            if (IS_L0) {
                size_t o = ((size_t)tp * Bn + row0 + 4 * rg + j) * Fn + cd * 32 + cu;
                outh[o] = hi_;
                outl[o] = lo_;
            }
        }
        lds_barrier();
    }
#pragma unroll
    for (int j = 0; j < 4; ++j) {
        size_t zr = (size_t)(row0 + 4 * rg + j) * 256;
        z[zr + ci_c * 32 + cu]       = hfin[j];
        z[zr + 128 + ci_c * 32 + cu] = cst[j];
    }
}

// ---------------------------------------------------------------------------
// Decoder: block = 512 thr (8 waves), 32 rows, grid 256. 4 sub-phases/step:
// A-compute (cells 0,1) | A-combine | B-compute (cells 2,3) | B-combine.
// ---------------------------------------------------------------------------
__global__ __launch_bounds__(512, 2)
void dec_kernel(const unsigned short* __restrict__ Whi, const unsigned short* __restrict__ Wlo,
                const float* __restrict__ bias, const float* __restrict__ z,
                float* __restrict__ xhat)
{
    __shared__ __align__(16) float gbuf[2][4][32][36];
    __shared__ __align__(16) unsigned short Yh[32][72], Yl[32][72];
    __shared__ __align__(16) unsigned short Mh[32][72], Ml[32][72];
    __shared__ __align__(16) unsigned short Hh[4][32][40], Hl[4][32][40];

    const int tid = threadIdx.x, w = tid >> 6, lane = tid & 63;
    const int wc = w >> 2, g = w & 3;     // compute: phase-A cell wc (B: wc+2), gate-type g
    const int n16 = lane & 15, kg = lane >> 4;
    const int row0 = blockIdx.x * 32;
    const int cc = tid >> 8, cu = tid & 31, rg = (tid >> 5) & 7;  // combine role

    bf8v WAh[2][3], WAl[2][3], WBh[2][3], WBl[2][3];
#pragma unroll
    for (int s = 0; s < 2; ++s)
#pragma unroll
        for (int ki = 0; ki < 3; ++ki) {
            size_t oA = (size_t)wc * 12288 + (g * 2 + s) * 1536 + ki * 512 + lane * 8;
            size_t oB = (size_t)(wc + 2) * 12288 + (g * 2 + s) * 1536 + ki * 512 + lane * 8;
            WAh[s][ki] = *(const bf8v*)(Whi + oA);
            WAl[s][ki] = *(const bf8v*)(Wlo + oA);
            WBh[s][ki] = *(const bf8v*)(Whi + oB);
            WBl[s][ki] = *(const bf8v*)(Wlo + oB);
        }
    const float bscale = (g == 2) ? 2.f * L2E : L2E;
    float bA[2], bB[2];
#pragma unroll
    for (int s = 0; s < 2; ++s) {
        bA[s] = bias[wc * 128 + (g * 2 + s) * 16 + n16] * bscale;
        bB[s] = bias[(wc + 2) * 128 + (g * 2 + s) * 16 + n16] * bscale;
    }
    float cstA[4], cstB[4];
#pragma unroll
    for (int j = 0; j < 4; ++j) {
        size_t zr = (size_t)(row0 + 4 * rg + j) * 256 + 128;
        cstA[j] = z[zr + cc * 32 + cu];
        cstB[j] = z[zr + (cc + 2) * 32 + cu];
    }
    {   // H init: 4*32*32/512 = 8 elems/thread
        int hc = tid >> 7, hrow = (tid >> 2) & 31, c8 = (tid & 3) * 8;
        const float* src = z + (size_t)(row0 + hrow) * 256 + hc * 32 + c8;
#pragma unroll
        for (int e = 0; e < 8; ++e)
            split_tr(src[e], Hh[hc][hrow][c8 + e], Hl[hc][hrow][c8 + e]);
    }
    for (int i = tid; i < 32 * 72; i += 512) { (&Yh[0][0])[i] = 0; (&Yl[0][0])[i] = 0; }
    lds_barrier();

    for (int t = 0; t < Tn; ++t) {
        // ---- A-compute: cells 0,1; v = [y | h[wc]] ----
        bf8v aH[2][3], aL[2][3];
#pragma unroll
        for (int mt = 0; mt < 2; ++mt) {
            int r = mt * 16 + n16;
            aH[mt][0] = *(const bf8v*)&Yh[r][kg * 8];
            aL[mt][0] = *(const bf8v*)&Yl[r][kg * 8];
            aH[mt][1] = *(const bf8v*)&Yh[r][32 + kg * 8];
            aL[mt][1] = *(const bf8v*)&Yl[r][32 + kg * 8];
            aH[mt][2] = *(const bf8v*)&Hh[wc][r][kg * 8];
            aL[mt][2] = *(const bf8v*)&Hl[wc][r][kg * 8];
        }
        f4v acc[2][2];
#pragma unroll
        for (int mt = 0; mt < 2; ++mt)
#pragma unroll
            for (int s = 0; s < 2; ++s)
                acc[mt][s] = (f4v){bA[s], bA[s], bA[s], bA[s]};
#pragma unroll
        for (int ki = 0; ki < 3; ++ki)
#pragma unroll
            for (int mt = 0; mt < 2; ++mt)
#pragma unroll
                for (int s = 0; s < 2; ++s) {
                    GM3(acc[mt][s], aH[mt][ki], aL[mt][ki], WAh[s][ki], WAl[s][ki]);
                }
#pragma unroll
        for (int mt = 0; mt < 2; ++mt)
#pragma unroll
            for (int s = 0; s < 2; ++s)
                *(f4v*)&gbuf[wc][g][s * 16 + n16][mt * 16 + kg * 4] = acc[mt][s];
        lds_barrier();
        // ---- A-combine ----
        {
            f4v gI = *(const f4v*)&gbuf[cc][0][cu][rg * 4];
            f4v gF = *(const f4v*)&gbuf[cc][1][cu][rg * 4];
            f4v gG = *(const f4v*)&gbuf[cc][2][cu][rg * 4];
            f4v gO = *(const f4v*)&gbuf[cc][3][cu][rg * 4];
#pragma unroll
            for (int j = 0; j < 4; ++j) {
                float h = lstm_one(gI[j], gF[j], gG[j], gO[j], cstA[j]);
                unsigned short hi_, lo_;
                split_tr(h, hi_, lo_);
                Mh[4 * rg + j][cc * 32 + cu] = hi_;
                Ml[4 * rg + j][cc * 32 + cu] = lo_;
                Hh[cc][4 * rg + j][cu] = hi_;
                Hl[cc][4 * rg + j][cu] = lo_;
            }
        }
        lds_barrier();
        // ---- B-compute: cells 2,3; v = [m | h[wc+2]] ----
#pragma unroll
        for (int mt = 0; mt < 2; ++mt) {
            int r = mt * 16 + n16;
            aH[mt][0] = *(const bf8v*)&Mh[r][kg * 8];
            aL[mt][0] = *(const bf8v*)&Ml[r][kg * 8];
            aH[mt][1] = *(const bf8v*)&Mh[r][32 + kg * 8];
            aL[mt][1] = *(const bf8v*)&Ml[r][32 + kg * 8];
            aH[mt][2] = *(const bf8v*)&Hh[wc + 2][r][kg * 8];
            aL[mt][2] = *(const bf8v*)&Hl[wc + 2][r][kg * 8];
        }
#pragma unroll
        for (int mt = 0; mt < 2; ++mt)
#pragma unroll
            for (int s = 0; s < 2; ++s)
                acc[mt][s] = (f4v){bB[s], bB[s], bB[s], bB[s]};
#pragma unroll
        for (int ki = 0; ki < 3; ++ki)
#pragma unroll
            for (int mt = 0; mt < 2; ++mt)
#pragma unroll
                for (int s = 0; s < 2; ++s) {
                    GM3(acc[mt][s], aH[mt][ki], aL[mt][ki], WBh[s][ki], WBl[s][ki]);
                }
#pragma unroll
        for (int mt = 0; mt < 2; ++mt)
#pragma unroll
            for (int s = 0; s < 2; ++s)
                *(f4v*)&gbuf[wc][g][s * 16 + n16][mt * 16 + kg * 4] = acc[mt][s];
        lds_barrier();
        // ---- B-combine ----
        {
            f4v gI = *(const f4v*)&gbuf[cc][0][cu][rg * 4];
            f4v gF = *(const f4v*)&gbuf[cc][1][cu][rg * 4];
            f4v gG = *(const f4v*)&gbuf[cc][2][cu][rg * 4];
            f4v gO = *(const f4v*)&gbuf[cc][3][cu][rg * 4];
#pragma unroll
            for (int j = 0; j < 4; ++j) {
                float h = lstm_one(gI[j], gF[j], gG[j], gO[j], cstB[j]);
                unsigned short hi_, lo_;
                split_tr(h, hi_, lo_);
                Yh[4 * rg + j][cc * 32 + cu] = hi_;
                Yl[4 * rg + j][cc * 32 + cu] = lo_;
                Hh[cc + 2][4 * rg + j][cu] = hi_;
                Hl[cc + 2][4 * rg + j][cu] = lo_;
                xhat[((size_t)(row0 + 4 * rg + j) * Tn + t) * Fn + cc * 32 + cu] = h;
            }
        }
        lds_barrier();
    }
}

extern "C" void kernel_launch(void* const* d_in, const int* in_sizes, int n_in,
                              void* d_out, int out_size, void* d_ws, size_t ws_size,
                              hipStream_t stream) {
    const float* x    = (const float*)d_in[0];
    const float* h0   = (const float*)d_in[1];
    const float* c0   = (const float*)d_in[2];
    const float* eWih = (const float*)d_in[3];
    const float* eWhh = (const float*)d_in[4];
    const float* eb   = (const float*)d_in[5];
    const float* dWih = (const float*)d_in[6];
    const float* dWhh = (const float*)d_in[7];
    const float* db   = (const float*)d_in[8];

    float* out = (float*)d_out;
    unsigned short* xs1h = (unsigned short*)d_out;            // [T,B,64] bf16 hi
    unsigned short* xs1l = xs1h + (size_t)XHAT_ELEMS;         // [T,B,64] bf16 lo
    float* zb = out + (size_t)XHAT_ELEMS;                     // [B,256] latent
    unsigned short* wsb = (unsigned short*)d_ws;              // 384 KB fragments

    hipLaunchKernelGGL(prep_kernel, dim3(48), dim3(256), 0, stream,
                       eWih, eWhh, dWih, dWhh, wsb);
    // encoder layer 0 (both dirs in one block): x -> xs1 hi/lo + z slots 0,1
    hipLaunchKernelGGL((enc_kernel<1>), dim3(Bn / 32), dim3(512), 0, stream,
                       x, (const unsigned short*)nullptr, (const unsigned short*)nullptr,
                       h0, c0, wsb, wsb + 49152, eb, 0, xs1h, xs1l, zb);
    // encoder layer 1: xs1 -> z slots 2,3
    hipLaunchKernelGGL((enc_kernel<0>), dim3(Bn / 32), dim3(512), 0, stream,
                       (const float*)nullptr, xs1h, xs1l,
                       h0, c0, wsb + 24576, wsb + 49152 + 24576, eb + 256, 1,
                       (unsigned short*)nullptr, (unsigned short*)nullptr, zb);
    // decoder: z -> x_hat (overwrites xs1 region)
    hipLaunchKernelGGL(dec_kernel, dim3(Bn / 32), dim3(512), 0, stream,
                       wsb + 98304, wsb + 147456, db, zb, out);
}

// Round 5
// 357.895 us; speedup vs baseline: 110.4240x; 1.1309x over previous
//
#include <hip/hip_runtime.h>
#include <cstddef>
#include <cstdint>

#define Tn 52
#define Fn 64
#define Hn 32
#define Bn 8192
#define XHAT_ELEMS (Bn * Tn * Fn)   // fp32 elems of x_hat == one packed-u32 [T,B,64] array
#define L2E 1.44269504088896340736f

typedef __attribute__((ext_vector_type(8))) short bf8v;        // 8 bf16 (4 VGPRs)
typedef __attribute__((ext_vector_type(4))) float f4v;         // 4 fp32 accum
typedef __attribute__((ext_vector_type(4))) unsigned int u4v;  // 4 packed hi|lo words

__device__ __forceinline__ f4v mfma_bf16(bf8v a, bf8v b, f4v c) {
    return __builtin_amdgcn_mfma_f32_16x16x32_bf16(a, b, c, 0, 0, 0);
}

// truncation split packed into one u32: v = hi + lo + O(2^-17 |v|)
__device__ __forceinline__ unsigned pack_hl(float v) {
    unsigned b  = __float_as_uint(v);
    unsigned hi = b & 0xFFFF0000u;
    float lf    = v - __uint_as_float(hi);
    return hi | (__float_as_uint(lf) >> 16);
}

__device__ __forceinline__ void split_tr(float v, unsigned short& hi, unsigned short& lo) {
    unsigned b = __float_as_uint(v);
    hi = (unsigned short)(b >> 16);
    float lf = v - __uint_as_float(b & 0xFFFF0000u);
    lo = (unsigned short)(__float_as_uint(lf) >> 16);
}

__device__ __forceinline__ void split8v(float4 a, float4 b, bf8v& h, bf8v& l) {
    float v[8] = {a.x, a.y, a.z, a.w, b.x, b.y, b.z, b.w};
#pragma unroll
    for (int j = 0; j < 8; ++j) {
        unsigned bb = __float_as_uint(v[j]);
        h[j] = (short)(bb >> 16);
        float lf = v[j] - __uint_as_float(bb & 0xFFFF0000u);
        l[j] = (short)(__float_as_uint(lf) >> 16);
    }
}

// 8 packed u32 -> hi/lo bf16 fragments via v_perm_b32
__device__ __forceinline__ void unpack8(u4v w0, u4v w1, bf8v& h, bf8v& l) {
    union { unsigned u[4]; bf8v v; } H, L;
#pragma unroll
    for (int k = 0; k < 2; ++k) {
        H.u[k]     = __builtin_amdgcn_perm(w0[2*k+1], w0[2*k], 0x07060302u);
        H.u[k + 2] = __builtin_amdgcn_perm(w1[2*k+1], w1[2*k], 0x07060302u);
        L.u[k]     = __builtin_amdgcn_perm(w0[2*k+1], w0[2*k], 0x05040100u);
        L.u[k + 2] = __builtin_amdgcn_perm(w1[2*k+1], w1[2*k], 0x05040100u);
    }
    h = H.v; l = L.v;
}

// barrier WITHOUT vmcnt drain: cross-thread data flows via LDS only; global
// prefetch loads / output stores stay in flight across it.
__device__ __forceinline__ void lds_barrier() {
    __builtin_amdgcn_sched_barrier(0);
    asm volatile("s_waitcnt lgkmcnt(0)" ::: "memory");
    __builtin_amdgcn_s_barrier();
    __builtin_amdgcn_sched_barrier(0);
}

// Gates pre-scaled by log2e (g-gate by 2*log2e). One rcp for c2, one for h.
__device__ __forceinline__ float lstm_one(float aI, float aF, float aG, float aO, float& cst) {
    float ei = exp2f(fminf(40.f, -aI));
    float ef = exp2f(fminf(40.f, -aF));
    float eg = exp2f(fminf(40.f, -aG));
    float eo = exp2f(fminf(40.f, -aO));
    float p   = (1.f + ei) * (1.f + eg);
    float num = cst * p + (1.f - eg) * (1.f + ef);
    float den = (1.f + ef) * p;
    float c2  = num * __builtin_amdgcn_rcpf(den);
    cst = c2;
    float e2 = exp2f(fminf(40.f, -2.f * L2E * c2));
    return (1.f - e2) * __builtin_amdgcn_rcpf((1.f + eo) * (1.f + e2));
}

// split-3: acc += aL*Wh + aH*Wl + aH*Wh
#define GM3(ACC, AH, AL, WHx, WLx)   \
    ACC = mfma_bf16(AL, WHx, ACC);   \
    ACC = mfma_bf16(AH, WLx, ACC);   \
    ACC = mfma_bf16(AH, WHx, ACC);

// ---------------------------------------------------------------------------
// Prep: weights -> fragment-ordered bf16 hi/lo in ws, pre-scaled by log2e
// (g-gate rows by 2*log2e). [grp][cell(4)][nt(8)][ki(3)][lane(64)][j(8)]
//   gate = nt*16 + (lane&15); k = ki*32 + (lane>>4)*8 + j
// ---------------------------------------------------------------------------
__global__ void prep_kernel(const float* __restrict__ eWih, const float* __restrict__ eWhh,
                            const float* __restrict__ dWih, const float* __restrict__ dWhh,
                            unsigned short* __restrict__ ws)
{
    int fid = blockIdx.x * 256 + threadIdx.x;
    if (fid >= 12288) return;
    int lane = fid & 63;
    int ki   = (fid >> 6) % 3;
    int nt   = (fid / 192) & 7;
    int cell = (fid / 1536) & 3;
    int grp  = fid / 6144;
    const float* Wih = grp ? dWih : eWih;
    const float* Whh = grp ? dWhh : eWhh;
    int gate = nt * 16 + (lane & 15);
    float scale = ((gate >> 5) == 2) ? 2.f * L2E : L2E;
    int k0 = ki * 32 + (lane >> 4) * 8;
    size_t base = (size_t)grp * 98304 + (size_t)cell * 12288 + nt * 1536 + ki * 512 + lane * 8;
#pragma unroll
    for (int j = 0; j < 8; ++j) {
        int k = k0 + j;
        float v = (k < 64) ? Wih[(size_t)cell * 8192 + gate * 64 + k]
                           : Whh[(size_t)cell * 4096 + gate * 32 + (k - 64)];
        v *= scale;
        split_tr(v, ws[base + j], ws[base + 49152 + j]);
    }
}

// ---------------------------------------------------------------------------
// Encoder layer: block = 256 thr (4 waves = dir x q-half), 16 rows, grid 512
// -> 2 blocks/CU (2 barrier domains). In-register combine (i,f,g,o of a unit
// land in one lane). 1 barrier/step. h-state double-buffered packed u32.
// ---------------------------------------------------------------------------
template<int IS_L0>
__global__ __launch_bounds__(256, 2)
void enc_kernel(const float* __restrict__ X, const unsigned* __restrict__ Xp,
                const float* __restrict__ h0, const float* __restrict__ c0,
                const unsigned short* __restrict__ Whi, const unsigned short* __restrict__ Wlo,
                const float* __restrict__ bias, int layer,
                unsigned* __restrict__ outp, float* __restrict__ z)
{
    __shared__ __align__(16) unsigned Hs[2][2][16][36];   // [dir][parity][row][unit pad36]
    const int tid = threadIdx.x, w = tid >> 6, lane = tid & 63;
    const int d = w >> 1, q = w & 1;
    const int a = lane & 15, kb = lane >> 4;
    const int u = q * 16 + a;
    const int row0 = blockIdx.x * 16;
    const int ci = 2 * layer + d;

    bf8v WH[4][3], WL[4][3];
#pragma unroll
    for (int g = 0; g < 4; ++g)
#pragma unroll
        for (int ki = 0; ki < 3; ++ki) {
            size_t off = (size_t)ci * 12288 + (2 * g + q) * 1536 + ki * 512 + lane * 8;
            WH[g][ki] = *(const bf8v*)(Whi + off);
            WL[g][ki] = *(const bf8v*)(Wlo + off);
        }
    float bj[4];
#pragma unroll
    for (int g = 0; g < 4; ++g)
        bj[g] = bias[ci * 128 + g * 32 + u] * ((g == 2) ? 2.f * L2E : L2E);
    float cst[4], hfin[4];
#pragma unroll
    for (int j = 0; j < 4; ++j)
        cst[j] = c0[((size_t)ci * Bn + row0 + 4 * kb + j) * Hn + u];

    {   // h0 -> parity-1 buffers: 2 dirs x 16 rows x 32 units / 256 thr = 4 each
        int dd = tid >> 7, rr = (tid >> 3) & 15, u4 = (tid & 7) * 4;
        const float* src = h0 + ((size_t)(2 * layer + dd) * Bn + row0 + rr) * Hn + u4;
#pragma unroll
        for (int e = 0; e < 4; ++e)
            Hs[dd][1][rr][u4 + e] = pack_hl(src[e]);
    }
    __syncthreads();

    const int grow = row0 + a;   // this lane's A-fragment row
    float4 p0, p1, p2, p3;
    u4v pw0, pw1, pw2, pw3;
    {
        int tt = d ? (Tn - 1) : 0;
        if (IS_L0) {
            const float* sp = X + ((size_t)grow * Tn + tt) * Fn;
            p0 = *(const float4*)(sp + kb * 8);      p1 = *(const float4*)(sp + kb * 8 + 4);
            p2 = *(const float4*)(sp + 32 + kb * 8); p3 = *(const float4*)(sp + 32 + kb * 8 + 4);
        } else {
            const unsigned* sp = Xp + ((size_t)tt * Bn + grow) * Fn;
            pw0 = *(const u4v*)(sp + kb * 8);      pw1 = *(const u4v*)(sp + kb * 8 + 4);
            pw2 = *(const u4v*)(sp + 32 + kb * 8); pw3 = *(const u4v*)(sp + 32 + kb * 8 + 4);
        }
    }

    for (int t = 0; t < Tn; ++t) {
        bf8v aH0, aL0, aH1, aL1, aH2, aL2;
        if (IS_L0) { split8v(p0, p1, aH0, aL0); split8v(p2, p3, aH1, aL1); }
        else       { unpack8(pw0, pw1, aH0, aL0); unpack8(pw2, pw3, aH1, aL1); }
        {   // prefetch t+1
            int tn = (t + 1 < Tn) ? t + 1 : t;
            int tt = d ? (Tn - 1 - tn) : tn;
            if (IS_L0) {
                const float* sp = X + ((size_t)grow * Tn + tt) * Fn;
                p0 = *(const float4*)(sp + kb * 8);      p1 = *(const float4*)(sp + kb * 8 + 4);
                p2 = *(const float4*)(sp + 32 + kb * 8); p3 = *(const float4*)(sp + 32 + kb * 8 + 4);
            } else {
                const unsigned* sp = Xp + ((size_t)tt * Bn + grow) * Fn;
                pw0 = *(const u4v*)(sp + kb * 8);      pw1 = *(const u4v*)(sp + kb * 8 + 4);
                pw2 = *(const u4v*)(sp + 32 + kb * 8); pw3 = *(const u4v*)(sp + 32 + kb * 8 + 4);
            }
        }
        {
            u4v hw0 = *(const u4v*)&Hs[d][(t & 1) ^ 1][a][kb * 8];
            u4v hw1 = *(const u4v*)&Hs[d][(t & 1) ^ 1][a][kb * 8 + 4];
            unpack8(hw0, hw1, aH2, aL2);
        }
        f4v acc[4];
#pragma unroll
        for (int g = 0; g < 4; ++g) acc[g] = (f4v){bj[g], bj[g], bj[g], bj[g]};
#pragma unroll
        for (int g = 0; g < 4; ++g) { GM3(acc[g], aH0, aL0, WH[g][0], WL[g][0]); }
#pragma unroll
        for (int g = 0; g < 4; ++g) { GM3(acc[g], aH1, aL1, WH[g][1], WL[g][1]); }
#pragma unroll
        for (int g = 0; g < 4; ++g) { GM3(acc[g], aH2, aL2, WH[g][2], WL[g][2]); }
        int tp = d ? (Tn - 1 - t) : t;
#pragma unroll
        for (int j = 0; j < 4; ++j) {
            float hh = lstm_one(acc[0][j], acc[1][j], acc[2][j], acc[3][j], cst[j]);
            hfin[j] = hh;
            unsigned hp = pack_hl(hh);
            Hs[d][t & 1][4 * kb + j][u] = hp;
            if (IS_L0)
                outp[((size_t)tp * Bn + row0 + 4 * kb + j) * Fn + d * 32 + u] = hp;
        }
        lds_barrier();
    }
#pragma unroll
    for (int j = 0; j < 4; ++j) {
        size_t zr = (size_t)(row0 + 4 * kb + j) * 256;
        z[zr + ci * 32 + u]       = hfin[j];
        z[zr + 128 + ci * 32 + u] = cst[j];
    }
}

// ---------------------------------------------------------------------------
// Decoder: block = 512 thr (8 waves), 32 rows as two 16-row groups, grid 256.
// Waves: P = phase (A cells 0/1, B cells 2/3), cl = cell, q = unit-half.
// Slot pipeline: every slot A works group g while B works group g^1 ->
// all waves busy, 1 barrier/slot (2/step). In-register combine, no gbuf.
// ---------------------------------------------------------------------------
__global__ __launch_bounds__(512, 2)
void dec_kernel(const unsigned short* __restrict__ Whi, const unsigned short* __restrict__ Wlo,
                const float* __restrict__ bias, const float* __restrict__ z,
                float* __restrict__ xhat)
{
    __shared__ __align__(16) unsigned Ys[2][2][16][68];    // [grp][parity][row][feat pad68]
    __shared__ __align__(16) unsigned Ms[2][16][68];       // [grp][row][feat]
    __shared__ __align__(16) unsigned Hs[4][2][2][16][36]; // [cell][grp][parity][row][unit]

    const int tid = threadIdx.x, w = tid >> 6, lane = tid & 63;
    const int P = w >> 2, cl = (w >> 1) & 1, q = w & 1;
    const int cell = P * 2 + cl;
    const int a = lane & 15, kb = lane >> 4, u = q * 16 + a;
    const int row0 = blockIdx.x * 32;

    bf8v WH[4][3], WL[4][3];
#pragma unroll
    for (int g = 0; g < 4; ++g)
#pragma unroll
        for (int ki = 0; ki < 3; ++ki) {
            size_t off = (size_t)cell * 12288 + (2 * g + q) * 1536 + ki * 512 + lane * 8;
            WH[g][ki] = *(const bf8v*)(Whi + off);
            WL[g][ki] = *(const bf8v*)(Wlo + off);
        }
    float bj[4];
#pragma unroll
    for (int g = 0; g < 4; ++g)
        bj[g] = bias[cell * 128 + g * 32 + u] * ((g == 2) ? 2.f * L2E : L2E);

    float cst0[4], cst1[4];
#pragma unroll
    for (int j = 0; j < 4; ++j) {
        cst0[j] = z[(size_t)(row0 +      4 * kb + j) * 256 + 128 + cell * 32 + u];
        cst1[j] = z[(size_t)(row0 + 16 + 4 * kb + j) * 256 + 128 + cell * 32 + u];
    }
    {   // h-init -> parity-1: 4 cells x 32 rows x 32 units / 512 thr = 8 each
        int ct = tid >> 7, rem = tid & 127, rr = rem >> 2, u8 = (rem & 3) * 8;
        const float* src = z + (size_t)(row0 + rr) * 256 + ct * 32 + u8;
#pragma unroll
        for (int e = 0; e < 8; ++e)
            Hs[ct][rr >> 4][1][rr & 15][u8 + e] = pack_hl(src[e]);
    }
    for (int i = tid; i < 2 * 16 * 68; i += 512) {   // y(-1) = 0 at parity 1
        int gI = (i >= 16 * 68) ? 1 : 0, rI = i - gI * (16 * 68);
        Ys[gI][1][rI / 68][rI % 68] = 0u;
    }
    __syncthreads();

    auto slotA = [&](int G, int tA, float (&cst)[4]) {
        int par = tA & 1, rpar = par ^ 1;
        u4v w0 = *(const u4v*)&Ys[G][rpar][a][kb * 8];
        u4v w1 = *(const u4v*)&Ys[G][rpar][a][kb * 8 + 4];
        u4v w2 = *(const u4v*)&Ys[G][rpar][a][32 + kb * 8];
        u4v w3 = *(const u4v*)&Ys[G][rpar][a][32 + kb * 8 + 4];
        u4v w4 = *(const u4v*)&Hs[cell][G][rpar][a][kb * 8];
        u4v w5 = *(const u4v*)&Hs[cell][G][rpar][a][kb * 8 + 4];
        bf8v aH0, aL0, aH1, aL1, aH2, aL2;
        unpack8(w0, w1, aH0, aL0); unpack8(w2, w3, aH1, aL1); unpack8(w4, w5, aH2, aL2);
        f4v acc[4];
#pragma unroll
        for (int g = 0; g < 4; ++g) acc[g] = (f4v){bj[g], bj[g], bj[g], bj[g]};
#pragma unroll
        for (int g = 0; g < 4; ++g) { GM3(acc[g], aH0, aL0, WH[g][0], WL[g][0]); }
#pragma unroll
        for (int g = 0; g < 4; ++g) { GM3(acc[g], aH1, aL1, WH[g][1], WL[g][1]); }
#pragma unroll
        for (int g = 0; g < 4; ++g) { GM3(acc[g], aH2, aL2, WH[g][2], WL[g][2]); }
#pragma unroll
        for (int j = 0; j < 4; ++j) {
            float hh = lstm_one(acc[0][j], acc[1][j], acc[2][j], acc[3][j], cst[j]);
            unsigned hp = pack_hl(hh);
            Ms[G][4 * kb + j][cell * 32 + u] = hp;
            Hs[cell][G][par][4 * kb + j][u] = hp;
        }
    };
    auto slotB = [&](int G, int tB, float (&cst)[4]) {
        int par = tB & 1, rpar = par ^ 1;
        u4v w0 = *(const u4v*)&Ms[G][a][kb * 8];
        u4v w1 = *(const u4v*)&Ms[G][a][kb * 8 + 4];
        u4v w2 = *(const u4v*)&Ms[G][a][32 + kb * 8];
        u4v w3 = *(const u4v*)&Ms[G][a][32 + kb * 8 + 4];
        u4v w4 = *(const u4v*)&Hs[cell][G][rpar][a][kb * 8];
        u4v w5 = *(const u4v*)&Hs[cell][G][rpar][a][kb * 8 + 4];
        bf8v aH0, aL0, aH1, aL1, aH2, aL2;
        unpack8(w0, w1, aH0, aL0); unpack8(w2, w3, aH1, aL1); unpack8(w4, w5, aH2, aL2);
        f4v acc[4];
#pragma unroll
        for (int g = 0; g < 4; ++g) acc[g] = (f4v){bj[g], bj[g], bj[g], bj[g]};
#pragma unroll
        for (int g = 0; g < 4; ++g) { GM3(acc[g], aH0, aL0, WH[g][0], WL[g][0]); }
#pragma unroll
        for (int g = 0; g < 4; ++g) { GM3(acc[g], aH1, aL1, WH[g][1], WL[g][1]); }
#pragma unroll
        for (int g = 0; g < 4; ++g) { GM3(acc[g], aH2, aL2, WH[g][2], WL[g][2]); }
#pragma unroll
        for (int j = 0; j < 4; ++j) {
            float hh = lstm_one(acc[0][j], acc[1][j], acc[2][j], acc[3][j], cst[j]);
            unsigned hp = pack_hl(hh);
            Ys[G][par][4 * kb + j][(cell - 2) * 32 + u] = hp;
            Hs[cell][G][par][4 * kb + j][u] = hp;
            xhat[((size_t)(row0 + G * 16 + 4 * kb + j) * Tn + tB) * Fn + (cell - 2) * 32 + u] = hh;
        }
    };

    for (int t = 0; t < Tn; ++t) {
        // slot even: A on G0(t), B on G1(t-1)
        if (P == 0)      slotA(0, t, cst0);
        else if (t > 0)  slotB(1, t - 1, cst1);
        lds_barrier();
        // slot odd: A on G1(t), B on G0(t)
        if (P == 0)      slotA(1, t, cst1);
        else             slotB(0, t, cst0);
        lds_barrier();
    }
    if (P == 1) slotB(1, Tn - 1, cst1);   // epilogue: G1's last step
}

extern "C" void kernel_launch(void* const* d_in, const int* in_sizes, int n_in,
                              void* d_out, int out_size, void* d_ws, size_t ws_size,
                              hipStream_t stream) {
    const float* x    = (const float*)d_in[0];
    const float* h0   = (const float*)d_in[1];
    const float* c0   = (const float*)d_in[2];
    const float* eWih = (const float*)d_in[3];
    const float* eWhh = (const float*)d_in[4];
    const float* eb   = (const float*)d_in[5];
    const float* dWih = (const float*)d_in[6];
    const float* dWhh = (const float*)d_in[7];
    const float* db   = (const float*)d_in[8];

    float* out = (float*)d_out;
    unsigned* xs1p = (unsigned*)d_out;               // [T,B,64] packed hi|lo, == x_hat bytes
    float* zb = out + (size_t)XHAT_ELEMS;            // [B,256] latent
    unsigned short* wsb = (unsigned short*)d_ws;     // 384 KB weight fragments

    hipLaunchKernelGGL(prep_kernel, dim3(48), dim3(256), 0, stream,
                       eWih, eWhh, dWih, dWhh, wsb);
    // encoder layer 0: x -> xs1 (packed) + z slots 0,1
    hipLaunchKernelGGL((enc_kernel<1>), dim3(Bn / 16), dim3(256), 0, stream,
                       x, (const unsigned*)nullptr, h0, c0,
                       wsb, wsb + 49152, eb, 0, xs1p, zb);
    // encoder layer 1: xs1 -> z slots 2,3
    hipLaunchKernelGGL((enc_kernel<0>), dim3(Bn / 16), dim3(256), 0, stream,
                       (const float*)nullptr, xs1p, h0, c0,
                       wsb, wsb + 49152, eb, 1, (unsigned*)nullptr, zb);
    // decoder: z -> x_hat (overwrites xs1 region)
    hipLaunchKernelGGL(dec_kernel, dim3(Bn / 32), dim3(512), 0, stream,
                       wsb + 98304, wsb + 147456, db, zb, out);
}